// Round 6
// baseline (125.573 us; speedup 1.0000x reference)
//
#include <hip/hip_runtime.h>
#include <math.h>

static __device__ __forceinline__ float frcp(float x){ return __builtin_amdgcn_rcpf(x); }
static __device__ __forceinline__ float fsq (float x){ return __builtin_amdgcn_sqrtf(x); }

// ---- DPP row-of-16 reductions ----
template<int CTRL>
static __device__ __forceinline__ float dppadd(float x){
  int t = __builtin_amdgcn_update_dpp(0, __float_as_int(x), CTRL, 0xf, 0xf, true);
  return x + __int_as_float(t);
}
template<int CTRL>
static __device__ __forceinline__ float dppmax(float x){
  int t = __builtin_amdgcn_update_dpp(__float_as_int(x), __float_as_int(x), CTRL, 0xf, 0xf, false);
  return fmaxf(x, __int_as_float(t));
}
template<int CTRL>
static __device__ __forceinline__ float dppmin(float x){
  int t = __builtin_amdgcn_update_dpp(__float_as_int(x), __float_as_int(x), CTRL, 0xf, 0xf, false);
  return fminf(x, __int_as_float(t));
}
// row sum -> broadcast row-wide via ds_swizzle (lane' = (lane&0x30)|slot15)
static __device__ __forceinline__ float rsum16(float x){
  x = dppadd<0x111>(x); x = dppadd<0x112>(x);
  x = dppadd<0x114>(x); x = dppadd<0x118>(x);
  return __int_as_float(__builtin_amdgcn_ds_swizzle(__float_as_int(x), 0x1F0));
}
static __device__ __forceinline__ float rmax16(float x){
  x = dppmax<0x111>(x); x = dppmax<0x112>(x);
  x = dppmax<0x114>(x); x = dppmax<0x118>(x);
  return __int_as_float(__builtin_amdgcn_ds_swizzle(__float_as_int(x), 0x1F0));
}
static __device__ __forceinline__ float rmin16(float x){
  x = dppmin<0x111>(x); x = dppmin<0x112>(x);
  x = dppmin<0x114>(x); x = dppmin<0x118>(x);
  return __int_as_float(__builtin_amdgcn_ds_swizzle(__float_as_int(x), 0x1F0));
}
// broadcast slot P of each row of 16: lane' = (lane&0x30)|P  (P literal)
#define BC(P, x) __int_as_float(__builtin_amdgcn_ds_swizzle(__float_as_int(x), 0x10 | ((P) << 5)))

__global__ void transpose_w(const float* __restrict__ W, float* __restrict__ Wt){
  int idx = blockIdx.x * 256 + threadIdx.x;
  if (idx < 60 * 48) { int f = idx / 48, j = idx - f * 48; Wt[j * 60 + f] = W[idx]; }
}

template<bool USEWT>
__global__ __launch_bounds__(256)
void traj_kernel(const float* __restrict__ coords,
                 const int* __restrict__ lengths,
                 const float* __restrict__ Wsrc,   // Wt [48][60] if USEWT else W [60][48]
                 const float* __restrict__ bias,
                 const float* __restrict__ lnw,
                 const float* __restrict__ lnb,
                 float* __restrict__ out, int B)
{
  __shared__ float lds_c[16 * 480];   // 30 KB: 16 trajectories x 48 rows x 10

  const int tid  = threadIdx.x;
  const int lane = tid & 63;
  const int s    = lane & 15;                       // slot (row-of-16 position)
  const int T    = ((tid >> 6) << 2) | (lane >> 4); // trajectory within block, 0..15
  const int blk  = blockIdx.x;
  const int grp  = blk * 16 + T;
  const bool bvalid = (grp < B);
  const int b = bvalid ? grp : (B - 1);

  // ---- stage block slab: 30720 B contiguous, coalesced dwordx4, each byte once ----
  {
    const int lastblk = (B - 1) >> 4;
    const int sblk = (blk <= lastblk) ? blk : lastblk;
    const float4* g = reinterpret_cast<const float4*>(coords + (size_t)sblk * 7680);
    float4* l = reinterpret_cast<float4*>(lds_c);
    const int nvec = min(1920, (B - sblk * 16) * 120);
#pragma unroll
    for (int it = 0; it < 8; ++it) {
      int idx = tid + it * 256;
      if (idx < nvec) l[idx] = g[idx];
    }
  }
  __syncthreads();

  const int n = lengths[b];                         // row-uniform VGPR, 4..48
  const int m = n - 1;
  const float* myc = lds_c + T * 480;

  // ---- read rows j=16q+s and j+1 from LDS ----
  float c[3][10], cn[3][10];
#pragma unroll
  for (int q = 0; q < 3; ++q) {
    const float2* p = reinterpret_cast<const float2*>(myc + (q * 16 + s) * 10);
#pragma unroll
    for (int k = 0; k < 5; ++k) { float2 v = p[k]; c[q][2*k] = v.x; c[q][2*k+1] = v.y; }
  }
#pragma unroll
  for (int q = 0; q < 3; ++q) {
    const int row = q * 16 + s + 1;
    if (row < 48) {
      const float2* p = reinterpret_cast<const float2*>(myc + row * 10);
#pragma unroll
      for (int k = 0; k < 5; ++k) { float2 v = p[k]; cn[q][2*k] = v.x; cn[q][2*k+1] = v.y; }
    } else {
#pragma unroll
      for (int k = 0; k < 10; ++k) cn[q][k] = 0.f;
    }
  }

  // ---- coord stats over rows < n ----
  float csl = 0.f, cs2l = 0.f;
#pragma unroll
  for (int q = 0; q < 3; ++q) {
    float t1 = 0.f, t2 = 0.f;
#pragma unroll
    for (int k = 0; k < 10; ++k) { t1 += c[q][k]; t2 = fmaf(c[q][k], c[q][k], t2); }
    const bool act = (q * 16 + s) < n;
    csl  += act ? t1 : 0.f;
    cs2l += act ? t2 : 0.f;
  }
  const float sum_c  = rsum16(csl);
  const float sum_c2 = rsum16(cs2l);

  // ---- total displacement: ||row_{n-1} - row_0|| ----
  float cc0[10];
#pragma unroll
  for (int k = 0; k < 10; ++k) cc0[k] = BC(0, c[0][k]);
  const int qs = (n - 1) >> 4, ssl = (n - 1) & 15;
  float tql = 0.f;
#pragma unroll
  for (int q = 0; q < 3; ++q) {
    float tq = 0.f;
#pragma unroll
    for (int k = 0; k < 10; ++k) { float t = c[q][k] - cc0[k]; tq = fmaf(t, t, tq); }
    tql = (s == ssl && q == qs) ? tq : tql;
  }
  const float tdq = rsum16(tql);
  const float total_disp = (tdq > 0.f) ? fsq(fmaxf(tdq, 1e-30f)) : 0.f;

  // ---- deltas ----
  const int half = m >> 1;
  float d[3][10], inv[3];
  float path_l=0.f, dm2_l=0.f, maxdm_l=0.f, sf_l=0.f, ss_l=0.f, uu_l=0.f;
  float uk[10];
#pragma unroll
  for (int k = 0; k < 10; ++k) uk[k] = 0.f;
#pragma unroll
  for (int q = 0; q < 3; ++q) {
    const int j = q * 16 + s;
    float ds_ = 0.f;
#pragma unroll
    for (int k = 0; k < 10; ++k) { float dd = cn[q][k] - c[q][k]; d[q][k] = dd; ds_ = fmaf(dd, dd, ds_); }
    const float sn = (ds_ > 0.f) ? fsq(fmaxf(ds_, 1e-30f)) : 0.f;   // safe_norm
    inv[q] = frcp(fmaxf(sn, 1e-8f));                                // 1/na
    const bool jm = j < m;
    const float dm = jm ? sn : 0.f;
    path_l += dm;
    dm2_l  += jm ? ds_ : 0.f;
    maxdm_l = fmaxf(maxdm_l, dm);
    sf_l += (j <= half) ? dm : 0.f;
    ss_l += (j >= half) ? dm : 0.f;
    const float invm = jm ? inv[q] : 0.f;
#pragma unroll
    for (int k = 0; k < 10; ++k) uk[k] = fmaf(d[q][k], invm, uk[k]);
    uu_l = fmaf(ds_ * invm, invm, uu_l);
  }

  // ---- neighbor inv via ds_bpermute rotate-within-row ----
  const int rotb = (((lane & 48) | ((lane + 1) & 15)) << 2);
  const float rinv0 = __int_as_float(__builtin_amdgcn_ds_bpermute(rotb, __float_as_int(inv[0])));
  const float rinv1 = __int_as_float(__builtin_amdgcn_ds_bpermute(rotb, __float_as_int(inv[1])));
  const float rinv2 = __int_as_float(__builtin_amdgcn_ds_bpermute(rotb, __float_as_int(inv[2])));
  float invn[3];
  invn[0] = (s < 15) ? rinv0 : rinv1;
  invn[1] = (s < 15) ? rinv1 : rinv2;
  invn[2] = (s < 15) ? rinv2 : 0.f;

  // ---- cos / curvature (d_{j+1} from LDS rows j+1, j+2) ----
  float cos_l=0.f, cos2_l=0.f, ng_l=0.f, maxc_l=-INFINITY, minc_l=INFINITY;
  float curv0 = 0.f;
#pragma unroll
  for (int q = 0; q < 3; ++q) {
    const int j = q * 16 + s;
    float dn[10];
    if (j + 2 < 48) {
      const float2* p = reinterpret_cast<const float2*>(myc + (j + 2) * 10);
#pragma unroll
      for (int k = 0; k < 5; ++k) { float2 v = p[k]; dn[2*k] = v.x - cn[q][2*k]; dn[2*k+1] = v.y - cn[q][2*k+1]; }
    } else {
#pragma unroll
      for (int k = 0; k < 10; ++k) dn[k] = 0.f;
    }
    float dot = 0.f;
#pragma unroll
    for (int k = 0; k < 10; ++k) dot = fmaf(d[q][k], dn[k], dot);
    const float cosv = dot * inv[q] * invn[q];
    const bool ca = j < (n - 2);
    const float cm = ca ? cosv : 0.f;
    cos_l += cm;
    cos2_l = fmaf(cm, cm, cos2_l);
    maxc_l = fmaxf(maxc_l, ca ? cosv : -INFINITY);
    minc_l = fminf(minc_l, ca ? cosv :  INFINITY);
    ng_l += (cm < 0.f) ? 1.f : 0.f;
    if (q == 0) curv0 = ca ? (1.f - cosv) : 0.f;
  }

  // ---- row reductions ----
  const float path_len = rsum16(path_l);
  const float sum_dm2  = rsum16(dm2_l);
  const float max_dm   = rmax16(maxdm_l);
  const float sum_f    = rsum16(sf_l);
  const float sum_s    = rsum16(ss_l);
  const float sum_cos  = rsum16(cos_l);
  const float sum_cos2 = rsum16(cos2_l);
  const float sum_ng   = rsum16(ng_l);
  const float max_cos  = rmax16(maxc_l);
  const float min_cos  = rmin16(minc_l);
  float Usq = 0.f;
#pragma unroll
  for (int k = 0; k < 10; ++k) { float Uk = rsum16(uk[k]); Usq = fmaf(Uk, Uk, Usq); }
  const float sum_uu = rsum16(uu_l);

  // ---- scalar features (row-uniform) ----
  const float EPSf = 1e-9f;
  const float nf = (float)n, mf = (float)m, ncf = (float)(n - 2);
  const float rncf = frcp(ncf);
  const float disp_ratio = total_disp * frcp(path_len + EPSf);
  const float sum_cv  = ncf - sum_cos;
  const float mean_cv = sum_cv * rncf;
  const float sum_cv2 = fmaf(-2.f, sum_cos, ncf) + sum_cos2;
  const float cv_var  = (sum_cv2 - ncf * mean_cv * mean_cv) * frcp(fmaxf(ncf - 1.f, 1.f));
  const float std_cv  = fsq(fmaxf(cv_var, 1e-30f));
  const float max_cv  = 1.f - min_cos;
  const float cv_rng  = max_cos - min_cos;
  const float mean_cs = sum_cos * rncf;
  const float dirchg  = sum_ng * rncf;
  const float fh = sum_f * frcp((float)(half + 1));
  const float sh = sum_s * frcp((float)(m - half));
  const float conv = (fh - sh) * frcp(fh + EPSf);
  const float npairs = mf * (mf - 1.f) * 0.5f;
  const float par = (Usq - sum_uu) * 0.5f * frcp(npairs);
  const float mean_dm = path_len * frcp(mf);
  const float dm_var = (sum_dm2 - mf * mean_dm * mean_dm) * frcp(mf - 1.f);
  const float std_dm = fsq(fmaxf(dm_var, 1e-30f));
  const float jump = (mean_dm > EPSf) ? max_dm * frcp(mean_dm) : 1.f;
  const float cnt = nf * 10.f;
  const float mean_co = sum_c * frcp(cnt);
  const float co_var = (sum_c2 - cnt * mean_co * mean_co) * frcp(cnt - 1.f);
  const float std_co = fsq(fmaxf(co_var, 1e-30f));

  // ---- 60 features (row-uniform in VGPRs) ----
  float feat[60];
  feat[0]  = total_disp;
  feat[1]  = path_len;
  feat[2]  = disp_ratio;
  feat[3]  = nf * 0.1f;
  feat[4]  = mean_cv;
  feat[5]  = max_cv;
  feat[6]  = std_cv;
  feat[7]  = cv_rng;
  feat[8]  = mean_cs;
  feat[9]  = min_cos;
  feat[10] = dirchg;
  feat[11] = disp_ratio;
  feat[12] = 1.f - disp_ratio;
  feat[13] = conv;
  feat[14] = par;
  feat[15] = jump;
  feat[16] = -conv;
  feat[17] = mean_dm;
  feat[18] = std_dm;
  feat[19] = mean_co;
  feat[20] = std_co;
#pragma unroll
  for (int k = 0; k < 10; ++k) feat[21 + k] = BC(0, d[0][k]);
#pragma unroll
  for (int k = 0; k < 10; ++k) feat[31 + k] = BC(1, d[0][k]);
#pragma unroll
  for (int k = 0; k < 10; ++k) feat[41 + k] = BC(2, d[0][k]);
  feat[51] = BC(0, curv0); feat[52] = BC(1, curv0); feat[53] = BC(2, curv0);
  feat[54] = BC(3, curv0); feat[55] = BC(4, curv0); feat[56] = BC(5, curv0);
  feat[57] = BC(6, curv0); feat[58] = BC(7, curv0); feat[59] = BC(8, curv0);

  // ---- h_j = feat @ W + b, split accumulators for ILP ----
  float h[3];
#pragma unroll
  for (int q = 0; q < 3; ++q) {
    const int j = q * 16 + s;
    float acc0 = bias[j], acc1 = 0.f;
    if (USEWT) {
      const float4* wr = reinterpret_cast<const float4*>(Wsrc + j * 60);
#pragma unroll
      for (int t = 0; t < 15; t += 2) {
        float4 w = wr[t];
        acc0 = fmaf(feat[4*t+0], w.x, acc0);
        acc0 = fmaf(feat[4*t+1], w.y, acc0);
        acc0 = fmaf(feat[4*t+2], w.z, acc0);
        acc0 = fmaf(feat[4*t+3], w.w, acc0);
        if (t + 1 < 15) {
          float4 w1 = wr[t+1];
          acc1 = fmaf(feat[4*t+4], w1.x, acc1);
          acc1 = fmaf(feat[4*t+5], w1.y, acc1);
          acc1 = fmaf(feat[4*t+6], w1.z, acc1);
          acc1 = fmaf(feat[4*t+7], w1.w, acc1);
        }
      }
    } else {
#pragma unroll
      for (int f = 0; f < 60; f += 2) {
        acc0 = fmaf(feat[f],   Wsrc[f * 48 + j], acc0);
        acc1 = fmaf(feat[f+1], Wsrc[(f+1) * 48 + j], acc1);
      }
    }
    h[q] = acc0 + acc1;
  }

  // ---- LayerNorm over the 48 outputs ----
  const float s1 = rsum16(h[0] + h[1] + h[2]);
  const float s2 = rsum16(fmaf(h[0], h[0], fmaf(h[1], h[1], h[2] * h[2])));
  const float mu  = s1 * (1.f / 48.f);
  const float var = fmaf(-mu, mu, s2 * (1.f / 48.f));
  const float rstd = __builtin_amdgcn_rsqf(var + 1e-5f);

  if (bvalid) {
#pragma unroll
    for (int q = 0; q < 3; ++q) {
      const int j = q * 16 + s;
      float x = (h[q] - mu) * rstd * lnw[j] + lnb[j];
      float x2 = x * x;
      float u  = 0.7978845608f * x * fmaf(0.044715f, x2, 1.f);
      float e  = __builtin_amdgcn_exp2f(u * 2.885390082f);   // e^{2u}
      float th = fmaf(-2.f, frcp(1.f + e), 1.f);
      out[(size_t)b * 48 + j] = 0.5f * x * (1.f + th);
    }
  }
}

extern "C" void kernel_launch(void* const* d_in, const int* in_sizes, int n_in,
                              void* d_out, int out_size, void* d_ws, size_t ws_size,
                              hipStream_t stream)
{
  const float* coords = (const float*)d_in[0];
  const int*   lengths= (const int*)d_in[1];
  const float* W      = (const float*)d_in[2];
  const float* bias   = (const float*)d_in[3];
  const float* lnw    = (const float*)d_in[4];
  const float* lnb    = (const float*)d_in[5];
  float* out = (float*)d_out;

  const int B = in_sizes[1];
  const int blocks = (B + 15) / 16;   // 16 trajectories per 256-thread block

  if (ws_size >= (size_t)(60 * 48 * sizeof(float))) {
    float* Wt = (float*)d_ws;
    transpose_w<<<12, 256, 0, stream>>>(W, Wt);
    traj_kernel<true><<<blocks, 256, 0, stream>>>(coords, lengths, Wt, bias, lnw, lnb, out, B);
  } else {
    traj_kernel<false><<<blocks, 256, 0, stream>>>(coords, lengths, W, bias, lnw, lnb, out, B);
  }
}